// Round 6
// baseline (313.953 us; speedup 1.0000x reference)
//
#include <hip/hip_runtime.h>
#include <math.h>

#define NACC 32
// acc layout: 0 cnt, 1 sw, 2-4 swx, 5-7 swy, 8-16 swyx[o*3+i],
//             17-19 sx, 20-22 sy, 23-31 syx[o*3+i]

typedef float f4 __attribute__((ext_vector_type(4)));

__device__ __forceinline__ void accum_point(float w, float x0, float x1, float x2,
                                            float y0, float y1, float y2, float* a) {
    a[0] += (w > 0.0f) ? 1.0f : 0.0f;
    a[1] += w;
    a[2] = fmaf(w, x0, a[2]); a[3] = fmaf(w, x1, a[3]); a[4] = fmaf(w, x2, a[4]);
    float wy0 = w * y0, wy1 = w * y1, wy2 = w * y2;
    a[5] += wy0; a[6] += wy1; a[7] += wy2;
    a[8]  = fmaf(wy0, x0, a[8]);  a[9]  = fmaf(wy0, x1, a[9]);  a[10] = fmaf(wy0, x2, a[10]);
    a[11] = fmaf(wy1, x0, a[11]); a[12] = fmaf(wy1, x1, a[12]); a[13] = fmaf(wy1, x2, a[13]);
    a[14] = fmaf(wy2, x0, a[14]); a[15] = fmaf(wy2, x1, a[15]); a[16] = fmaf(wy2, x2, a[16]);
    a[17] += x0; a[18] += x1; a[19] += x2;
    a[20] += y0; a[21] += y1; a[22] += y2;
    a[23] = fmaf(y0, x0, a[23]); a[24] = fmaf(y0, x1, a[24]); a[25] = fmaf(y0, x2, a[25]);
    a[26] = fmaf(y1, x0, a[26]); a[27] = fmaf(y1, x1, a[27]); a[28] = fmaf(y1, x2, a[28]);
    a[29] = fmaf(y2, x0, a[29]); a[30] = fmaf(y2, x1, a[30]); a[31] = fmaf(y2, x2, a[31]);
}

__device__ __forceinline__ double det3(const double m[3][3]) {
    return m[0][0] * (m[1][1] * m[2][2] - m[1][2] * m[2][1])
         - m[0][1] * (m[1][0] * m[2][2] - m[1][2] * m[2][0])
         + m[0][2] * (m[1][0] * m[2][1] - m[1][1] * m[2][0]);
}

// Fused reduce + finalize. Fusion mechanism = last-block atomic ticket
// (verified correct in r4; r4's 5x slowdown was the volatile-asm load loop,
// NOT the ticket). Hot loop = plain compiler-scheduled loads (verified 41us
// in r1 at this exact grid shape). Cooperative launch does NOT work under
// the harness's graph capture (r5: kernel never ran) — do not use.
__global__ __launch_bounds__(256) void kabsch_fused(
    const float* __restrict__ c0, const float* __restrict__ c1,
    const float* __restrict__ w, int N, float* __restrict__ partials, int nblocks,
    unsigned* __restrict__ ticket, float* __restrict__ out) {
    __shared__ float wred[4][NACC];

    float a[NACC];
    #pragma unroll
    for (int i = 0; i < NACC; ++i) a[i] = 0.0f;

    const int t = threadIdx.x;
    const int lane = t & 63, wave = t >> 6;
    const f4* __restrict__ A4 = (const f4*)c0;
    const f4* __restrict__ B4 = (const f4*)c1;
    const f4* __restrict__ W4 = (const f4*)w;

    const int ngrp = N >> 2;
    const int stride = gridDim.x << 8;   // gridDim.x * 256
    for (int g = (blockIdx.x << 8) + t; g < ngrp; g += stride) {
        int i3 = 3 * g;
        f4 a0 = A4[i3], a1 = A4[i3 + 1], a2 = A4[i3 + 2];
        f4 b0 = B4[i3], b1 = B4[i3 + 1], b2 = B4[i3 + 2];
        f4 vw = W4[g];
        accum_point(vw.x, a0.x, a0.y, a0.z, b0.x, b0.y, b0.z, a);
        accum_point(vw.y, a0.w, a1.x, a1.y, b0.w, b1.x, b1.y, a);
        accum_point(vw.z, a1.z, a1.w, a2.x, b1.z, b1.w, b2.x, a);
        accum_point(vw.w, a2.y, a2.z, a2.w, b2.y, b2.z, b2.w, a);
    }
    // tail points (N % 4) — never taken for N = 4M, correctness-general
    if (blockIdx.x == 0 && t == 0) {
        for (int i = (N >> 2) << 2; i < N; ++i)
            accum_point(w[i], c0[3*i], c0[3*i+1], c0[3*i+2],
                        c1[3*i], c1[3*i+1], c1[3*i+2], a);
    }

    // ---- multi-value butterfly wave reduction: 32 accs in 32 shuffles.
    // final mapping lane -> acc = bitrev5(lane&31). ----
    {
        int hi;
        hi = lane & 1;
        #pragma unroll
        for (int i = 0; i < 16; ++i) {
            float send = hi ? a[i] : a[i + 16];
            float recv = __shfl_xor(send, 1, 64);
            a[i] = (hi ? a[i + 16] : a[i]) + recv;
        }
        hi = lane & 2;
        #pragma unroll
        for (int i = 0; i < 8; ++i) {
            float send = hi ? a[i] : a[i + 8];
            float recv = __shfl_xor(send, 2, 64);
            a[i] = (hi ? a[i + 8] : a[i]) + recv;
        }
        hi = lane & 4;
        #pragma unroll
        for (int i = 0; i < 4; ++i) {
            float send = hi ? a[i] : a[i + 4];
            float recv = __shfl_xor(send, 4, 64);
            a[i] = (hi ? a[i + 4] : a[i]) + recv;
        }
        hi = lane & 8;
        #pragma unroll
        for (int i = 0; i < 2; ++i) {
            float send = hi ? a[i] : a[i + 2];
            float recv = __shfl_xor(send, 8, 64);
            a[i] = (hi ? a[i + 2] : a[i]) + recv;
        }
        hi = lane & 16;
        {
            float send = hi ? a[0] : a[1];
            float recv = __shfl_xor(send, 16, 64);
            a[0] = (hi ? a[1] : a[0]) + recv;
        }
        a[0] += __shfl_xor(a[0], 32, 64);
    }
    if (lane < 32) {
        int acc = ((lane & 1) << 4) | ((lane & 2) << 2) | (lane & 4)
                | ((lane & 8) >> 2) | ((lane & 16) >> 4);  // bitrev5
        wred[wave][acc] = a[0];
    }
    __syncthreads();
    if (t < NACC)
        partials[t * nblocks + blockIdx.x] =
            wred[0][t] + wred[1][t] + wred[2][t] + wred[3][t];

    // ---- last-block ticket: device-scope release/acquire ----
    __threadfence();            // make this block's partials device-visible
    __syncthreads();            // all threads' stores/fences done before the atomic
    __shared__ unsigned amlast;
    if (t == 0) amlast = atomicAdd(ticket, 1u);
    __syncthreads();
    if (amlast != (unsigned)(nblocks - 1)) return;
    __threadfence();            // acquire: see all other blocks' partials

    // ---- finalize (last-arriving block only) ----
    // wave w owns accs 8w..8w+7; lane-parallel float4 row sums.
    double dd[8];
    #pragma unroll
    for (int i = 0; i < 8; ++i) dd[i] = 0.0;
    if ((nblocks & 3) == 0) {
        const int nb4 = nblocks >> 2;
        const f4* __restrict__ p4 = (const f4*)partials;
        #pragma unroll
        for (int i = 0; i < 8; ++i) {
            int row = (wave << 3) + i;
            for (int j = lane; j < nb4; j += 64) {
                f4 v = p4[row * nb4 + j];
                dd[i] += ((double)v.x + (double)v.y) + ((double)v.z + (double)v.w);
            }
        }
    } else {
        #pragma unroll
        for (int i = 0; i < 8; ++i) {
            int row = (wave << 3) + i;
            for (int j = lane; j < nblocks; j += 64)
                dd[i] += (double)partials[row * nblocks + j];
        }
    }
    #pragma unroll
    for (int off = 32; off > 0; off >>= 1) {
        #pragma unroll
        for (int i = 0; i < 8; ++i) dd[i] += __shfl_down(dd[i], off, 64);
    }
    __shared__ double sm[NACC];
    if (lane == 0) {
        #pragma unroll
        for (int i = 0; i < 8; ++i) sm[(wave << 3) + i] = dd[i];
    }
    __syncthreads();
    if (t != 0) return;

    double d[NACC];
    #pragma unroll
    for (int i = 0; i < NACC; ++i) d[i] = sm[i];

    const double EPSF = (double)1.1920929e-7f;  // float32 eps
    double cnt = d[0];
    double W = d[1];
    double swx[3] = { d[2], d[3], d[4] };
    double swy[3] = { d[5], d[6], d[7] };
    double swyx[9];
    for (int i = 0; i < 9; ++i) swyx[i] = d[8 + i];
    bool nep = cnt < 3.0;
    if (nep) {  // weights += EPS everywhere, applied analytically
        W += EPSF * (double)N;
        for (int i = 0; i < 3; ++i) { swx[i] += EPSF * d[17 + i]; swy[i] += EPSF * d[20 + i]; }
        for (int i = 0; i < 9; ++i) swyx[i] += EPSF * d[23 + i];
    }

    double mx[3], my[3];
    for (int i = 0; i < 3; ++i) { mx[i] = swx[i] / W; my[i] = swy[i] / W; }
    double S[3][3];
    for (int o = 0; o < 3; ++o)
        for (int i = 0; i < 3; ++i)
            S[o][i] = swyx[o * 3 + i] / W - my[o] * mx[i];

    // Jacobi eigendecomposition of B = S^T S  ->  V, lam
    double Bm[3][3], V[3][3];
    for (int i = 0; i < 3; ++i)
        for (int j = 0; j < 3; ++j) {
            double acc = 0.0;
            for (int k = 0; k < 3; ++k) acc += S[k][i] * S[k][j];
            Bm[i][j] = acc;
            V[i][j] = (i == j) ? 1.0 : 0.0;
        }
    for (int sweep = 0; sweep < 30; ++sweep) {
        double off2 = Bm[0][1]*Bm[0][1] + Bm[0][2]*Bm[0][2] + Bm[1][2]*Bm[1][2];
        double diag2 = Bm[0][0]*Bm[0][0] + Bm[1][1]*Bm[1][1] + Bm[2][2]*Bm[2][2];
        if (off2 <= diag2 * 1e-32 + 1e-300) break;
        for (int pair = 0; pair < 3; ++pair) {
            int p = (pair == 2) ? 1 : 0;
            int q = (pair == 0) ? 1 : 2;
            double apq = Bm[p][q];
            if (fabs(apq) < 1e-300) continue;
            double theta = (Bm[q][q] - Bm[p][p]) / (2.0 * apq);
            double tt = ((theta >= 0.0) ? 1.0 : -1.0) / (fabs(theta) + sqrt(1.0 + theta * theta));
            double c = 1.0 / sqrt(1.0 + tt * tt);
            double sn = tt * c;
            for (int k = 0; k < 3; ++k) {
                double bkp = Bm[k][p], bkq = Bm[k][q];
                Bm[k][p] = c * bkp - sn * bkq;
                Bm[k][q] = sn * bkp + c * bkq;
            }
            for (int k = 0; k < 3; ++k) {
                double bpk = Bm[p][k], bqk = Bm[q][k];
                Bm[p][k] = c * bpk - sn * bqk;
                Bm[q][k] = sn * bpk + c * bqk;
            }
            for (int k = 0; k < 3; ++k) {
                double vkp = V[k][p], vkq = V[k][q];
                V[k][p] = c * vkp - sn * vkq;
                V[k][q] = sn * vkp + c * vkq;
            }
        }
    }
    double lam[3] = { Bm[0][0], Bm[1][1], Bm[2][2] };
    for (int i = 0; i < 2; ++i)
        for (int j = i + 1; j < 3; ++j)
            if (lam[j] > lam[i]) {
                double tl = lam[i]; lam[i] = lam[j]; lam[j] = tl;
                for (int k = 0; k < 3; ++k) { double tv = V[k][i]; V[k][i] = V[k][j]; V[k][j] = tv; }
            }
    double sig[3];
    for (int i = 0; i < 3; ++i) sig[i] = sqrt(fmax(lam[i], 0.0));

    double U[3][3];
    for (int i = 0; i < 3; ++i) {
        double u0 = S[0][0]*V[0][i] + S[0][1]*V[1][i] + S[0][2]*V[2][i];
        double u1 = S[1][0]*V[0][i] + S[1][1]*V[1][i] + S[1][2]*V[2][i];
        double u2 = S[2][0]*V[0][i] + S[2][1]*V[1][i] + S[2][2]*V[2][i];
        double nrm = sqrt(u0*u0 + u1*u1 + u2*u2);
        if (nrm > 1e-150) {
            U[0][i] = u0 / nrm; U[1][i] = u1 / nrm; U[2][i] = u2 / nrm;
        } else if (i == 0) {
            U[0][0] = 1.0; U[1][0] = 0.0; U[2][0] = 0.0;
        } else if (i == 1) {
            double e0 = (fabs(U[0][0]) < 0.9) ? 1.0 : 0.0;
            double e1 = 1.0 - e0;
            double dp = e0 * U[0][0] + e1 * U[1][0];
            double v0 = e0 - dp * U[0][0], v1 = e1 - dp * U[1][0], v2 = -dp * U[2][0];
            double n2 = sqrt(v0*v0 + v1*v1 + v2*v2);
            U[0][1] = v0 / n2; U[1][1] = v1 / n2; U[2][1] = v2 / n2;
        } else {
            U[0][2] = U[1][0]*U[2][1] - U[2][0]*U[1][1];
            U[1][2] = U[2][0]*U[0][1] - U[0][0]*U[2][1];
            U[2][2] = U[0][0]*U[1][1] - U[1][0]*U[0][1];
        }
    }

    double tol = sig[0] * 3.0 * EPSF;
    int rank = (sig[0] > tol) + (sig[1] > tol) + (sig[2] > tol);
    double detS = det3(S);
    double det_mul = det3(U) * det3(V);
    double sign_full = (detS < 0.0) ? -1.0 : 1.0;
    double sign_def = (fabs(det_mul + 1.0) <= 1.00001e-5) ? -1.0 : 1.0;
    double s = (rank > 2) ? sign_full : sign_def;

    double R[3][3];
    for (int o = 0; o < 3; ++o)
        for (int i = 0; i < 3; ++i)
            R[o][i] = U[o][0]*V[i][0] + U[o][1]*V[i][1] + s * U[o][2]*V[i][2];
    double tv[3];
    for (int o = 0; o < 3; ++o)
        tv[o] = my[o] - (R[o][0]*mx[0] + R[o][1]*mx[1] + R[o][2]*mx[2]);

    for (int o = 0; o < 3; ++o) {
        out[o * 4 + 0] = (float)R[o][0];
        out[o * 4 + 1] = (float)R[o][1];
        out[o * 4 + 2] = (float)R[o][2];
        out[o * 4 + 3] = (float)tv[o];
    }
    out[12] = 0.0f; out[13] = 0.0f; out[14] = 0.0f; out[15] = 1.0f;
    out[16] = nep ? 1.0f : 0.0f;
}

extern "C" void kernel_launch(void* const* d_in, const int* in_sizes, int n_in,
                              void* d_out, int out_size, void* d_ws, size_t ws_size,
                              hipStream_t stream) {
    const float* c0 = (const float*)d_in[0];
    const float* c1 = (const float*)d_in[1];
    const float* w  = (const float*)d_in[2];
    float* out = (float*)d_out;
    int N = in_sizes[2];  // B=1: weights has N elements

    int ngrp = N >> 2;
    int blocks = (ngrp + 255) >> 8;
    if (blocks > 1024) blocks = 1024;   // N=4M -> 1024 blocks, 4 groups/thread
    if (blocks < 1) blocks = 1;
    size_t need = (size_t)blocks * NACC * sizeof(float) + sizeof(unsigned);
    if (need > ws_size) {
        blocks = (int)((ws_size - sizeof(unsigned)) / (NACC * sizeof(float)));
        if (blocks < 1) blocks = 1;
    }
    float* partials = (float*)d_ws;   // layout: [acc][block] (transposed)
    unsigned* ticket = (unsigned*)((char*)d_ws + (size_t)blocks * NACC * sizeof(float));

    hipMemsetAsync(ticket, 0, sizeof(unsigned), stream);
    kabsch_fused<<<blocks, 256, 0, stream>>>(c0, c1, w, N, partials, blocks, ticket, out);
}

// Round 7
// 153.158 us; speedup vs baseline: 2.0499x; 2.0499x over previous
//
#include <hip/hip_runtime.h>
#include <math.h>

#define NACC 32
// acc layout: 0 cnt, 1 sw, 2-4 swx, 5-7 swy, 8-16 swyx[o*3+i],
//             17-19 sx, 20-22 sy, 23-31 syx[o*3+i]

typedef float f4 __attribute__((ext_vector_type(4)));

// Two-kernel structure is mandatory on this harness:
//  - ticket+threadfence fusion: +170us constant (r4/r6, traffic-independent)
//  - hipLaunchCooperativeKernel: never executes under graph capture (r5)
// Reduce loop = r1's verified 40.8us form. Do not reintroduce volatile-asm
// load batching in the loop (r4: killed cross-iteration overlap).

__device__ __forceinline__ void accum_point(float w, float x0, float x1, float x2,
                                            float y0, float y1, float y2, float* a) {
    a[0] += (w > 0.0f) ? 1.0f : 0.0f;
    a[1] += w;
    a[2] = fmaf(w, x0, a[2]); a[3] = fmaf(w, x1, a[3]); a[4] = fmaf(w, x2, a[4]);
    float wy0 = w * y0, wy1 = w * y1, wy2 = w * y2;
    a[5] += wy0; a[6] += wy1; a[7] += wy2;
    a[8]  = fmaf(wy0, x0, a[8]);  a[9]  = fmaf(wy0, x1, a[9]);  a[10] = fmaf(wy0, x2, a[10]);
    a[11] = fmaf(wy1, x0, a[11]); a[12] = fmaf(wy1, x1, a[12]); a[13] = fmaf(wy1, x2, a[13]);
    a[14] = fmaf(wy2, x0, a[14]); a[15] = fmaf(wy2, x1, a[15]); a[16] = fmaf(wy2, x2, a[16]);
    a[17] += x0; a[18] += x1; a[19] += x2;
    a[20] += y0; a[21] += y1; a[22] += y2;
    a[23] = fmaf(y0, x0, a[23]); a[24] = fmaf(y0, x1, a[24]); a[25] = fmaf(y0, x2, a[25]);
    a[26] = fmaf(y1, x0, a[26]); a[27] = fmaf(y1, x1, a[27]); a[28] = fmaf(y1, x2, a[28]);
    a[29] = fmaf(y2, x0, a[29]); a[30] = fmaf(y2, x1, a[30]); a[31] = fmaf(y2, x2, a[31]);
}

__global__ __launch_bounds__(256) void kabsch_reduce(
    const float* __restrict__ c0, const float* __restrict__ c1,
    const float* __restrict__ w, int N, float* __restrict__ partials, int nblocks) {
    __shared__ float wred[4][NACC];

    float a[NACC];
    #pragma unroll
    for (int i = 0; i < NACC; ++i) a[i] = 0.0f;

    const int t = threadIdx.x;
    const int lane = t & 63, wave = t >> 6;
    const f4* __restrict__ A4 = (const f4*)c0;
    const f4* __restrict__ B4 = (const f4*)c1;
    const f4* __restrict__ W4 = (const f4*)w;

    const int ngrp = N >> 2;
    const int stride = gridDim.x << 8;   // gridDim.x * 256
    for (int g = (blockIdx.x << 8) + t; g < ngrp; g += stride) {
        int i3 = 3 * g;
        f4 a0 = A4[i3], a1 = A4[i3 + 1], a2 = A4[i3 + 2];
        f4 b0 = B4[i3], b1 = B4[i3 + 1], b2 = B4[i3 + 2];
        f4 vw = W4[g];
        accum_point(vw.x, a0.x, a0.y, a0.z, b0.x, b0.y, b0.z, a);
        accum_point(vw.y, a0.w, a1.x, a1.y, b0.w, b1.x, b1.y, a);
        accum_point(vw.z, a1.z, a1.w, a2.x, b1.z, b1.w, b2.x, a);
        accum_point(vw.w, a2.y, a2.z, a2.w, b2.y, b2.z, b2.w, a);
    }
    // tail points (N % 4) — never taken for N = 4M, correctness-general
    if (blockIdx.x == 0 && t == 0) {
        for (int i = (N >> 2) << 2; i < N; ++i)
            accum_point(w[i], c0[3*i], c0[3*i+1], c0[3*i+2],
                        c1[3*i], c1[3*i+1], c1[3*i+2], a);
    }

    // ---- multi-value butterfly wave reduction: 32 accs in 32 shuffles.
    // final mapping lane -> acc = bitrev5(lane&31). ----
    {
        int hi;
        hi = lane & 1;
        #pragma unroll
        for (int i = 0; i < 16; ++i) {
            float send = hi ? a[i] : a[i + 16];
            float recv = __shfl_xor(send, 1, 64);
            a[i] = (hi ? a[i + 16] : a[i]) + recv;
        }
        hi = lane & 2;
        #pragma unroll
        for (int i = 0; i < 8; ++i) {
            float send = hi ? a[i] : a[i + 8];
            float recv = __shfl_xor(send, 2, 64);
            a[i] = (hi ? a[i + 8] : a[i]) + recv;
        }
        hi = lane & 4;
        #pragma unroll
        for (int i = 0; i < 4; ++i) {
            float send = hi ? a[i] : a[i + 4];
            float recv = __shfl_xor(send, 4, 64);
            a[i] = (hi ? a[i + 4] : a[i]) + recv;
        }
        hi = lane & 8;
        #pragma unroll
        for (int i = 0; i < 2; ++i) {
            float send = hi ? a[i] : a[i + 2];
            float recv = __shfl_xor(send, 8, 64);
            a[i] = (hi ? a[i + 2] : a[i]) + recv;
        }
        hi = lane & 16;
        {
            float send = hi ? a[0] : a[1];
            float recv = __shfl_xor(send, 16, 64);
            a[0] = (hi ? a[1] : a[0]) + recv;
        }
        a[0] += __shfl_xor(a[0], 32, 64);
    }
    if (lane < 32) {
        int acc = ((lane & 1) << 4) | ((lane & 2) << 2) | (lane & 4)
                | ((lane & 8) >> 2) | ((lane & 16) >> 4);  // bitrev5
        wred[wave][acc] = a[0];
    }
    __syncthreads();
    if (t < NACC)
        partials[t * nblocks + blockIdx.x] =
            wred[0][t] + wred[1][t] + wred[2][t] + wred[3][t];
}

__device__ __forceinline__ double det3(const double m[3][3]) {
    return m[0][0] * (m[1][1] * m[2][2] - m[1][2] * m[2][1])
         - m[0][1] * (m[1][0] * m[2][2] - m[1][2] * m[2][0])
         + m[0][2] * (m[1][0] * m[2][1] - m[1][1] * m[2][0]);
}

// Lean finalize: wave w owns accs 8w..8w+7, f4 partial reads, dd[8] doubles.
// This exact summation + scalar-math code was validated inside r6's fused
// kernel (absmax = 0); here it runs as its own (cheap) dispatch.
__global__ __launch_bounds__(256) void kabsch_finalize(
    const float* __restrict__ partials, int nblocks, int N, float* __restrict__ out) {
    const int t = threadIdx.x;
    const int lane = t & 63, wave = t >> 6;

    double dd[8];
    #pragma unroll
    for (int i = 0; i < 8; ++i) dd[i] = 0.0;
    if ((nblocks & 3) == 0) {
        const int nb4 = nblocks >> 2;
        const f4* __restrict__ p4 = (const f4*)partials;
        #pragma unroll
        for (int i = 0; i < 8; ++i) {
            int row = (wave << 3) + i;
            for (int j = lane; j < nb4; j += 64) {
                f4 v = p4[row * nb4 + j];
                dd[i] += ((double)v.x + (double)v.y) + ((double)v.z + (double)v.w);
            }
        }
    } else {
        #pragma unroll
        for (int i = 0; i < 8; ++i) {
            int row = (wave << 3) + i;
            for (int j = lane; j < nblocks; j += 64)
                dd[i] += (double)partials[row * nblocks + j];
        }
    }
    #pragma unroll
    for (int off = 32; off > 0; off >>= 1) {
        #pragma unroll
        for (int i = 0; i < 8; ++i) dd[i] += __shfl_down(dd[i], off, 64);
    }
    __shared__ double sm[NACC];
    if (lane == 0) {
        #pragma unroll
        for (int i = 0; i < 8; ++i) sm[(wave << 3) + i] = dd[i];
    }
    __syncthreads();
    if (t != 0) return;

    double d[NACC];
    #pragma unroll
    for (int i = 0; i < NACC; ++i) d[i] = sm[i];

    const double EPSF = (double)1.1920929e-7f;  // float32 eps
    double cnt = d[0];
    double W = d[1];
    double swx[3] = { d[2], d[3], d[4] };
    double swy[3] = { d[5], d[6], d[7] };
    double swyx[9];
    for (int i = 0; i < 9; ++i) swyx[i] = d[8 + i];
    bool nep = cnt < 3.0;
    if (nep) {  // weights += EPS everywhere, applied analytically
        W += EPSF * (double)N;
        for (int i = 0; i < 3; ++i) { swx[i] += EPSF * d[17 + i]; swy[i] += EPSF * d[20 + i]; }
        for (int i = 0; i < 9; ++i) swyx[i] += EPSF * d[23 + i];
    }

    double mx[3], my[3];
    for (int i = 0; i < 3; ++i) { mx[i] = swx[i] / W; my[i] = swy[i] / W; }
    double S[3][3];
    for (int o = 0; o < 3; ++o)
        for (int i = 0; i < 3; ++i)
            S[o][i] = swyx[o * 3 + i] / W - my[o] * mx[i];

    // Jacobi eigendecomposition of B = S^T S  ->  V, lam
    double Bm[3][3], V[3][3];
    for (int i = 0; i < 3; ++i)
        for (int j = 0; j < 3; ++j) {
            double acc = 0.0;
            for (int k = 0; k < 3; ++k) acc += S[k][i] * S[k][j];
            Bm[i][j] = acc;
            V[i][j] = (i == j) ? 1.0 : 0.0;
        }
    for (int sweep = 0; sweep < 30; ++sweep) {
        double off2 = Bm[0][1]*Bm[0][1] + Bm[0][2]*Bm[0][2] + Bm[1][2]*Bm[1][2];
        double diag2 = Bm[0][0]*Bm[0][0] + Bm[1][1]*Bm[1][1] + Bm[2][2]*Bm[2][2];
        if (off2 <= diag2 * 1e-32 + 1e-300) break;
        for (int pair = 0; pair < 3; ++pair) {
            int p = (pair == 2) ? 1 : 0;
            int q = (pair == 0) ? 1 : 2;
            double apq = Bm[p][q];
            if (fabs(apq) < 1e-300) continue;
            double theta = (Bm[q][q] - Bm[p][p]) / (2.0 * apq);
            double tt = ((theta >= 0.0) ? 1.0 : -1.0) / (fabs(theta) + sqrt(1.0 + theta * theta));
            double c = 1.0 / sqrt(1.0 + tt * tt);
            double sn = tt * c;
            for (int k = 0; k < 3; ++k) {
                double bkp = Bm[k][p], bkq = Bm[k][q];
                Bm[k][p] = c * bkp - sn * bkq;
                Bm[k][q] = sn * bkp + c * bkq;
            }
            for (int k = 0; k < 3; ++k) {
                double bpk = Bm[p][k], bqk = Bm[q][k];
                Bm[p][k] = c * bpk - sn * bqk;
                Bm[q][k] = sn * bpk + c * bqk;
            }
            for (int k = 0; k < 3; ++k) {
                double vkp = V[k][p], vkq = V[k][q];
                V[k][p] = c * vkp - sn * vkq;
                V[k][q] = sn * vkp + c * vkq;
            }
        }
    }
    double lam[3] = { Bm[0][0], Bm[1][1], Bm[2][2] };
    for (int i = 0; i < 2; ++i)
        for (int j = i + 1; j < 3; ++j)
            if (lam[j] > lam[i]) {
                double tl = lam[i]; lam[i] = lam[j]; lam[j] = tl;
                for (int k = 0; k < 3; ++k) { double tv = V[k][i]; V[k][i] = V[k][j]; V[k][j] = tv; }
            }
    double sig[3];
    for (int i = 0; i < 3; ++i) sig[i] = sqrt(fmax(lam[i], 0.0));

    double U[3][3];
    for (int i = 0; i < 3; ++i) {
        double u0 = S[0][0]*V[0][i] + S[0][1]*V[1][i] + S[0][2]*V[2][i];
        double u1 = S[1][0]*V[0][i] + S[1][1]*V[1][i] + S[1][2]*V[2][i];
        double u2 = S[2][0]*V[0][i] + S[2][1]*V[1][i] + S[2][2]*V[2][i];
        double nrm = sqrt(u0*u0 + u1*u1 + u2*u2);
        if (nrm > 1e-150) {
            U[0][i] = u0 / nrm; U[1][i] = u1 / nrm; U[2][i] = u2 / nrm;
        } else if (i == 0) {
            U[0][0] = 1.0; U[1][0] = 0.0; U[2][0] = 0.0;
        } else if (i == 1) {
            double e0 = (fabs(U[0][0]) < 0.9) ? 1.0 : 0.0;
            double e1 = 1.0 - e0;
            double dp = e0 * U[0][0] + e1 * U[1][0];
            double v0 = e0 - dp * U[0][0], v1 = e1 - dp * U[1][0], v2 = -dp * U[2][0];
            double n2 = sqrt(v0*v0 + v1*v1 + v2*v2);
            U[0][1] = v0 / n2; U[1][1] = v1 / n2; U[2][1] = v2 / n2;
        } else {
            U[0][2] = U[1][0]*U[2][1] - U[2][0]*U[1][1];
            U[1][2] = U[2][0]*U[0][1] - U[0][0]*U[2][1];
            U[2][2] = U[0][0]*U[1][1] - U[1][0]*U[0][1];
        }
    }

    double tol = sig[0] * 3.0 * EPSF;
    int rank = (sig[0] > tol) + (sig[1] > tol) + (sig[2] > tol);
    double detS = det3(S);
    double det_mul = det3(U) * det3(V);
    double sign_full = (detS < 0.0) ? -1.0 : 1.0;
    double sign_def = (fabs(det_mul + 1.0) <= 1.00001e-5) ? -1.0 : 1.0;
    double s = (rank > 2) ? sign_full : sign_def;

    double R[3][3];
    for (int o = 0; o < 3; ++o)
        for (int i = 0; i < 3; ++i)
            R[o][i] = U[o][0]*V[i][0] + U[o][1]*V[i][1] + s * U[o][2]*V[i][2];
    double tv[3];
    for (int o = 0; o < 3; ++o)
        tv[o] = my[o] - (R[o][0]*mx[0] + R[o][1]*mx[1] + R[o][2]*mx[2]);

    for (int o = 0; o < 3; ++o) {
        out[o * 4 + 0] = (float)R[o][0];
        out[o * 4 + 1] = (float)R[o][1];
        out[o * 4 + 2] = (float)R[o][2];
        out[o * 4 + 3] = (float)tv[o];
    }
    out[12] = 0.0f; out[13] = 0.0f; out[14] = 0.0f; out[15] = 1.0f;
    out[16] = nep ? 1.0f : 0.0f;
}

extern "C" void kernel_launch(void* const* d_in, const int* in_sizes, int n_in,
                              void* d_out, int out_size, void* d_ws, size_t ws_size,
                              hipStream_t stream) {
    const float* c0 = (const float*)d_in[0];
    const float* c1 = (const float*)d_in[1];
    const float* w  = (const float*)d_in[2];
    float* out = (float*)d_out;
    int N = in_sizes[2];  // B=1: weights has N elements

    int ngrp = N >> 2;
    int blocks = (ngrp + 255) >> 8;
    if (blocks > 1024) blocks = 1024;   // N=4M -> 1024 blocks, 4 groups/thread (r1: 40.8us)
    if (blocks < 1) blocks = 1;
    size_t need = (size_t)blocks * NACC * sizeof(float);
    if (need > ws_size) {
        blocks = (int)(ws_size / (NACC * sizeof(float)));
        if (blocks < 1) blocks = 1;
    }
    float* partials = (float*)d_ws;   // layout: [acc][block] (transposed)

    kabsch_reduce<<<blocks, 256, 0, stream>>>(c0, c1, w, N, partials, blocks);
    kabsch_finalize<<<1, 256, 0, stream>>>(partials, blocks, N, out);
}

// Round 8
// 150.659 us; speedup vs baseline: 2.0839x; 1.0166x over previous
//
#include <hip/hip_runtime.h>
#include <math.h>

#define NACC 32
// acc layout: 0 cnt, 1 sw, 2-4 swx, 5-7 swy, 8-16 swyx[o*3+i],
//             17-19 sx, 20-22 sy, 23-31 syx[o*3+i]

typedef float f4 __attribute__((ext_vector_type(4)));

// Fence-free fused reduce+finalize.
//  - r4/r6 fusion cost 170us: per-block __threadfence() = buffer_wbl2 (L2
//    writeback-inv), serialized per XCD. NOT the ticket.
//  - Here ALL cross-block data moves via device-scope atomics (coherent at
//    the coherence point, no cache flush needed): f32 fadd accumulators +
//    relaxed u32 ticket + fadd(0,sc0) reads. No __threadfence anywhere.
//  - Inline-asm global_atomic_add_f32: guarantees native instruction (HIP
//    atomicAdd(float*) may emit a CAS loop -> contention disaster).
//  - Hot loop = r1's verified 40.8us form (plain compiler-scheduled loads;
//    volatile-asm batching regressed 5x in r4).
//  - Cooperative launch never executes under graph capture (r5). Don't.

__device__ __forceinline__ void accum_point(float w, float x0, float x1, float x2,
                                            float y0, float y1, float y2, float* a) {
    a[0] += (w > 0.0f) ? 1.0f : 0.0f;
    a[1] += w;
    a[2] = fmaf(w, x0, a[2]); a[3] = fmaf(w, x1, a[3]); a[4] = fmaf(w, x2, a[4]);
    float wy0 = w * y0, wy1 = w * y1, wy2 = w * y2;
    a[5] += wy0; a[6] += wy1; a[7] += wy2;
    a[8]  = fmaf(wy0, x0, a[8]);  a[9]  = fmaf(wy0, x1, a[9]);  a[10] = fmaf(wy0, x2, a[10]);
    a[11] = fmaf(wy1, x0, a[11]); a[12] = fmaf(wy1, x1, a[12]); a[13] = fmaf(wy1, x2, a[13]);
    a[14] = fmaf(wy2, x0, a[14]); a[15] = fmaf(wy2, x1, a[15]); a[16] = fmaf(wy2, x2, a[16]);
    a[17] += x0; a[18] += x1; a[19] += x2;
    a[20] += y0; a[21] += y1; a[22] += y2;
    a[23] = fmaf(y0, x0, a[23]); a[24] = fmaf(y0, x1, a[24]); a[25] = fmaf(y0, x2, a[25]);
    a[26] = fmaf(y1, x0, a[26]); a[27] = fmaf(y1, x1, a[27]); a[28] = fmaf(y1, x2, a[28]);
    a[29] = fmaf(y2, x0, a[29]); a[30] = fmaf(y2, x1, a[30]); a[31] = fmaf(y2, x2, a[31]);
}

__device__ __forceinline__ double det3(const double m[3][3]) {
    return m[0][0] * (m[1][1] * m[2][2] - m[1][2] * m[2][1])
         - m[0][1] * (m[1][0] * m[2][2] - m[1][2] * m[2][0])
         + m[0][2] * (m[1][0] * m[2][1] - m[1][1] * m[2][0]);
}

__global__ __launch_bounds__(256) void kabsch_fused(
    const float* __restrict__ c0, const float* __restrict__ c1,
    const float* __restrict__ w, int N, float* __restrict__ acc32, int nblocks,
    unsigned* __restrict__ ticket, float* __restrict__ out) {
    __shared__ float wred[4][NACC];

    float a[NACC];
    #pragma unroll
    for (int i = 0; i < NACC; ++i) a[i] = 0.0f;

    const int t = threadIdx.x;
    const int lane = t & 63, wave = t >> 6;
    const f4* __restrict__ A4 = (const f4*)c0;
    const f4* __restrict__ B4 = (const f4*)c1;
    const f4* __restrict__ W4 = (const f4*)w;

    const int ngrp = N >> 2;
    const int stride = gridDim.x << 8;   // gridDim.x * 256
    for (int g = (blockIdx.x << 8) + t; g < ngrp; g += stride) {
        int i3 = 3 * g;
        f4 a0 = A4[i3], a1 = A4[i3 + 1], a2 = A4[i3 + 2];
        f4 b0 = B4[i3], b1 = B4[i3 + 1], b2 = B4[i3 + 2];
        f4 vw = W4[g];
        accum_point(vw.x, a0.x, a0.y, a0.z, b0.x, b0.y, b0.z, a);
        accum_point(vw.y, a0.w, a1.x, a1.y, b0.w, b1.x, b1.y, a);
        accum_point(vw.z, a1.z, a1.w, a2.x, b1.z, b1.w, b2.x, a);
        accum_point(vw.w, a2.y, a2.z, a2.w, b2.y, b2.z, b2.w, a);
    }
    // tail points (N % 4) — never taken for N = 4M, correctness-general
    if (blockIdx.x == 0 && t == 0) {
        for (int i = (N >> 2) << 2; i < N; ++i)
            accum_point(w[i], c0[3*i], c0[3*i+1], c0[3*i+2],
                        c1[3*i], c1[3*i+1], c1[3*i+2], a);
    }

    // ---- multi-value butterfly wave reduction: 32 accs in 32 shuffles.
    // final mapping lane -> acc = bitrev5(lane&31). ----
    {
        int hi;
        hi = lane & 1;
        #pragma unroll
        for (int i = 0; i < 16; ++i) {
            float send = hi ? a[i] : a[i + 16];
            float recv = __shfl_xor(send, 1, 64);
            a[i] = (hi ? a[i + 16] : a[i]) + recv;
        }
        hi = lane & 2;
        #pragma unroll
        for (int i = 0; i < 8; ++i) {
            float send = hi ? a[i] : a[i + 8];
            float recv = __shfl_xor(send, 2, 64);
            a[i] = (hi ? a[i + 8] : a[i]) + recv;
        }
        hi = lane & 4;
        #pragma unroll
        for (int i = 0; i < 4; ++i) {
            float send = hi ? a[i] : a[i + 4];
            float recv = __shfl_xor(send, 4, 64);
            a[i] = (hi ? a[i + 4] : a[i]) + recv;
        }
        hi = lane & 8;
        #pragma unroll
        for (int i = 0; i < 2; ++i) {
            float send = hi ? a[i] : a[i + 2];
            float recv = __shfl_xor(send, 8, 64);
            a[i] = (hi ? a[i + 2] : a[i]) + recv;
        }
        hi = lane & 16;
        {
            float send = hi ? a[0] : a[1];
            float recv = __shfl_xor(send, 16, 64);
            a[0] = (hi ? a[1] : a[0]) + recv;
        }
        a[0] += __shfl_xor(a[0], 32, 64);
    }
    if (lane < 32) {
        int acc = ((lane & 1) << 4) | ((lane & 2) << 2) | (lane & 4)
                | ((lane & 8) >> 2) | ((lane & 16) >> 4);  // bitrev5
        wred[wave][acc] = a[0];
    }
    __syncthreads();

    // ---- publish via native device-scope f32 atomic add (no fence) ----
    if (t < NACC) {
        float val = wred[0][t] + wred[1][t] + wred[2][t] + wred[3][t];
        float* p = acc32 + t;
        asm volatile("global_atomic_add_f32 %0, %1, off"
                     :: "v"(p), "v"(val) : "memory");
    }
    asm volatile("s_waitcnt vmcnt(0)" ::: "memory");  // fadds performed
    __syncthreads();
    __shared__ unsigned amlast;
    if (t == 0) amlast = atomicAdd(ticket, 1u);       // relaxed, coherent
    __syncthreads();
    if (amlast != (unsigned)(nblocks - 1)) return;

    // ---- last-arriving block: read totals via atomic fadd(0), sc0=return old
    __shared__ float tot[NACC];
    if (t < NACC) {
        float* p = acc32 + t;
        float zero = 0.0f, old;
        asm volatile("global_atomic_add_f32 %0, %1, %2, off sc0"
                     : "=&v"(old) : "v"(p), "v"(zero) : "memory");
        asm volatile("s_waitcnt vmcnt(0)" ::: "memory");
        tot[t] = old;
    }
    __syncthreads();
    if (t != 0) return;

    double d[NACC];
    #pragma unroll
    for (int i = 0; i < NACC; ++i) d[i] = (double)tot[i];

    const double EPSF = (double)1.1920929e-7f;  // float32 eps
    double cnt = d[0];
    double W = d[1];
    double swx[3] = { d[2], d[3], d[4] };
    double swy[3] = { d[5], d[6], d[7] };
    double swyx[9];
    for (int i = 0; i < 9; ++i) swyx[i] = d[8 + i];
    bool nep = cnt < 3.0;
    if (nep) {  // weights += EPS everywhere, applied analytically
        W += EPSF * (double)N;
        for (int i = 0; i < 3; ++i) { swx[i] += EPSF * d[17 + i]; swy[i] += EPSF * d[20 + i]; }
        for (int i = 0; i < 9; ++i) swyx[i] += EPSF * d[23 + i];
    }

    double mx[3], my[3];
    for (int i = 0; i < 3; ++i) { mx[i] = swx[i] / W; my[i] = swy[i] / W; }
    double S[3][3];
    for (int o = 0; o < 3; ++o)
        for (int i = 0; i < 3; ++i)
            S[o][i] = swyx[o * 3 + i] / W - my[o] * mx[i];

    // Jacobi eigendecomposition of B = S^T S  ->  V, lam
    double Bm[3][3], V[3][3];
    for (int i = 0; i < 3; ++i)
        for (int j = 0; j < 3; ++j) {
            double acc = 0.0;
            for (int k = 0; k < 3; ++k) acc += S[k][i] * S[k][j];
            Bm[i][j] = acc;
            V[i][j] = (i == j) ? 1.0 : 0.0;
        }
    for (int sweep = 0; sweep < 30; ++sweep) {
        double off2 = Bm[0][1]*Bm[0][1] + Bm[0][2]*Bm[0][2] + Bm[1][2]*Bm[1][2];
        double diag2 = Bm[0][0]*Bm[0][0] + Bm[1][1]*Bm[1][1] + Bm[2][2]*Bm[2][2];
        if (off2 <= diag2 * 1e-32 + 1e-300) break;
        for (int pair = 0; pair < 3; ++pair) {
            int p = (pair == 2) ? 1 : 0;
            int q = (pair == 0) ? 1 : 2;
            double apq = Bm[p][q];
            if (fabs(apq) < 1e-300) continue;
            double theta = (Bm[q][q] - Bm[p][p]) / (2.0 * apq);
            double tt = ((theta >= 0.0) ? 1.0 : -1.0) / (fabs(theta) + sqrt(1.0 + theta * theta));
            double c = 1.0 / sqrt(1.0 + tt * tt);
            double sn = tt * c;
            for (int k = 0; k < 3; ++k) {
                double bkp = Bm[k][p], bkq = Bm[k][q];
                Bm[k][p] = c * bkp - sn * bkq;
                Bm[k][q] = sn * bkp + c * bkq;
            }
            for (int k = 0; k < 3; ++k) {
                double bpk = Bm[p][k], bqk = Bm[q][k];
                Bm[p][k] = c * bpk - sn * bqk;
                Bm[q][k] = sn * bpk + c * bqk;
            }
            for (int k = 0; k < 3; ++k) {
                double vkp = V[k][p], vkq = V[k][q];
                V[k][p] = c * vkp - sn * vkq;
                V[k][q] = sn * vkp + c * vkq;
            }
        }
    }
    double lam[3] = { Bm[0][0], Bm[1][1], Bm[2][2] };
    for (int i = 0; i < 2; ++i)
        for (int j = i + 1; j < 3; ++j)
            if (lam[j] > lam[i]) {
                double tl = lam[i]; lam[i] = lam[j]; lam[j] = tl;
                for (int k = 0; k < 3; ++k) { double tv = V[k][i]; V[k][i] = V[k][j]; V[k][j] = tv; }
            }
    double sig[3];
    for (int i = 0; i < 3; ++i) sig[i] = sqrt(fmax(lam[i], 0.0));

    double U[3][3];
    for (int i = 0; i < 3; ++i) {
        double u0 = S[0][0]*V[0][i] + S[0][1]*V[1][i] + S[0][2]*V[2][i];
        double u1 = S[1][0]*V[0][i] + S[1][1]*V[1][i] + S[1][2]*V[2][i];
        double u2 = S[2][0]*V[0][i] + S[2][1]*V[1][i] + S[2][2]*V[2][i];
        double nrm = sqrt(u0*u0 + u1*u1 + u2*u2);
        if (nrm > 1e-150) {
            U[0][i] = u0 / nrm; U[1][i] = u1 / nrm; U[2][i] = u2 / nrm;
        } else if (i == 0) {
            U[0][0] = 1.0; U[1][0] = 0.0; U[2][0] = 0.0;
        } else if (i == 1) {
            double e0 = (fabs(U[0][0]) < 0.9) ? 1.0 : 0.0;
            double e1 = 1.0 - e0;
            double dp = e0 * U[0][0] + e1 * U[1][0];
            double v0 = e0 - dp * U[0][0], v1 = e1 - dp * U[1][0], v2 = -dp * U[2][0];
            double n2 = sqrt(v0*v0 + v1*v1 + v2*v2);
            U[0][1] = v0 / n2; U[1][1] = v1 / n2; U[2][1] = v2 / n2;
        } else {
            U[0][2] = U[1][0]*U[2][1] - U[2][0]*U[1][1];
            U[1][2] = U[2][0]*U[0][1] - U[0][0]*U[2][1];
            U[2][2] = U[0][0]*U[1][1] - U[1][0]*U[0][1];
        }
    }

    double tol = sig[0] * 3.0 * EPSF;
    int rank = (sig[0] > tol) + (sig[1] > tol) + (sig[2] > tol);
    double detS = det3(S);
    double det_mul = det3(U) * det3(V);
    double sign_full = (detS < 0.0) ? -1.0 : 1.0;
    double sign_def = (fabs(det_mul + 1.0) <= 1.00001e-5) ? -1.0 : 1.0;
    double s = (rank > 2) ? sign_full : sign_def;

    double R[3][3];
    for (int o = 0; o < 3; ++o)
        for (int i = 0; i < 3; ++i)
            R[o][i] = U[o][0]*V[i][0] + U[o][1]*V[i][1] + s * U[o][2]*V[i][2];
    double tv[3];
    for (int o = 0; o < 3; ++o)
        tv[o] = my[o] - (R[o][0]*mx[0] + R[o][1]*mx[1] + R[o][2]*mx[2]);

    for (int o = 0; o < 3; ++o) {
        out[o * 4 + 0] = (float)R[o][0];
        out[o * 4 + 1] = (float)R[o][1];
        out[o * 4 + 2] = (float)R[o][2];
        out[o * 4 + 3] = (float)tv[o];
    }
    out[12] = 0.0f; out[13] = 0.0f; out[14] = 0.0f; out[15] = 1.0f;
    out[16] = nep ? 1.0f : 0.0f;
}

extern "C" void kernel_launch(void* const* d_in, const int* in_sizes, int n_in,
                              void* d_out, int out_size, void* d_ws, size_t ws_size,
                              hipStream_t stream) {
    const float* c0 = (const float*)d_in[0];
    const float* c1 = (const float*)d_in[1];
    const float* w  = (const float*)d_in[2];
    float* out = (float*)d_out;
    int N = in_sizes[2];  // B=1: weights has N elements

    int ngrp = N >> 2;
    int blocks = (ngrp + 255) >> 8;
    if (blocks > 1024) blocks = 1024;   // N=4M -> 1024 blocks, 4 groups/thread
    if (blocks < 1) blocks = 1;

    float* acc32 = (float*)d_ws;                       // 32 f32 accumulators
    unsigned* ticket = (unsigned*)((char*)d_ws + NACC * sizeof(float));

    hipMemsetAsync(d_ws, 0, NACC * sizeof(float) + sizeof(unsigned), stream);
    kabsch_fused<<<blocks, 256, 0, stream>>>(c0, c1, w, N, acc32, blocks, ticket, out);
}

// Round 9
// 146.562 us; speedup vs baseline: 2.1421x; 1.0280x over previous
//
#include <hip/hip_runtime.h>
#include <math.h>

#define NACC 32
#define ACC_STRIDE 32   // pad each f32 accumulator to its own 128B cache line
// acc layout: 0 cnt, 1 sw, 2-4 swx, 5-7 swy, 8-16 swyx[o*3+i],
//             17-19 sx, 20-22 sy, 23-31 syx[o*3+i]

typedef float f4 __attribute__((ext_vector_type(4)));

// Fence-free fused reduce+finalize (r8: verified correct, 150.7us total).
//  - NO __threadfence: r4/r6 showed per-block wbl2 costs ~170us.
//  - Cross-block data via device-scope atomics only (coherent, no flush).
//  - r9 changes: (a) accumulators padded to 1 line each (r8 put all 32
//    atomics in ONE 128B line -> serialized coherence point);
//    (b) launch_bounds(256,1) + named-register prefetch rotation to let
//    the compiler hold next iteration's 7 loads in flight (VGPR cap 48
//    previously forced ~2-load batches). Plain HIP, no volatile asm in
//    the loop (r4: volatile asm kills compiler pipelining).

__device__ __forceinline__ void accum_point(float w, float x0, float x1, float x2,
                                            float y0, float y1, float y2, float* a) {
    a[0] += (w > 0.0f) ? 1.0f : 0.0f;
    a[1] += w;
    a[2] = fmaf(w, x0, a[2]); a[3] = fmaf(w, x1, a[3]); a[4] = fmaf(w, x2, a[4]);
    float wy0 = w * y0, wy1 = w * y1, wy2 = w * y2;
    a[5] += wy0; a[6] += wy1; a[7] += wy2;
    a[8]  = fmaf(wy0, x0, a[8]);  a[9]  = fmaf(wy0, x1, a[9]);  a[10] = fmaf(wy0, x2, a[10]);
    a[11] = fmaf(wy1, x0, a[11]); a[12] = fmaf(wy1, x1, a[12]); a[13] = fmaf(wy1, x2, a[13]);
    a[14] = fmaf(wy2, x0, a[14]); a[15] = fmaf(wy2, x1, a[15]); a[16] = fmaf(wy2, x2, a[16]);
    a[17] += x0; a[18] += x1; a[19] += x2;
    a[20] += y0; a[21] += y1; a[22] += y2;
    a[23] = fmaf(y0, x0, a[23]); a[24] = fmaf(y0, x1, a[24]); a[25] = fmaf(y0, x2, a[25]);
    a[26] = fmaf(y1, x0, a[26]); a[27] = fmaf(y1, x1, a[27]); a[28] = fmaf(y1, x2, a[28]);
    a[29] = fmaf(y2, x0, a[29]); a[30] = fmaf(y2, x1, a[30]); a[31] = fmaf(y2, x2, a[31]);
}

__device__ __forceinline__ double det3(const double m[3][3]) {
    return m[0][0] * (m[1][1] * m[2][2] - m[1][2] * m[2][1])
         - m[0][1] * (m[1][0] * m[2][2] - m[1][2] * m[2][0])
         + m[0][2] * (m[1][0] * m[2][1] - m[1][1] * m[2][0]);
}

__global__ __launch_bounds__(256, 1) void kabsch_fused(
    const float* __restrict__ c0, const float* __restrict__ c1,
    const float* __restrict__ w, int N, float* __restrict__ acc32, int nblocks,
    unsigned* __restrict__ ticket, float* __restrict__ out) {
    __shared__ float wred[4][NACC];

    float a[NACC];
    #pragma unroll
    for (int i = 0; i < NACC; ++i) a[i] = 0.0f;

    const int t = threadIdx.x;
    const int lane = t & 63, wave = t >> 6;
    const f4* __restrict__ A4 = (const f4*)c0;
    const f4* __restrict__ B4 = (const f4*)c1;
    const f4* __restrict__ W4 = (const f4*)w;

    // ---- software-pipelined hot loop: load iter k+1 into fresh named regs
    // before consuming iter k. Compile-time-indexed variables only. ----
    const int ngrp = N >> 2;
    const int stride = gridDim.x << 8;   // gridDim.x * 256
    {
        int g = (blockIdx.x << 8) + t;
        if (g < ngrp) {
            const f4* pa = A4 + 3 * (size_t)g;
            const f4* pb = B4 + 3 * (size_t)g;
            f4 ca0 = pa[0], ca1 = pa[1], ca2 = pa[2];
            f4 cb0 = pb[0], cb1 = pb[1], cb2 = pb[2];
            f4 cw  = W4[g];
            for (int gn = g + stride; ; gn += stride) {
                const bool more = gn < ngrp;
                f4 na0, na1, na2, nb0, nb1, nb2, nw;
                if (more) {
                    const f4* qa = A4 + 3 * (size_t)gn;
                    const f4* qb = B4 + 3 * (size_t)gn;
                    na0 = qa[0]; na1 = qa[1]; na2 = qa[2];
                    nb0 = qb[0]; nb1 = qb[1]; nb2 = qb[2];
                    nw  = W4[gn];
                }
                accum_point(cw.x, ca0.x, ca0.y, ca0.z, cb0.x, cb0.y, cb0.z, a);
                accum_point(cw.y, ca0.w, ca1.x, ca1.y, cb0.w, cb1.x, cb1.y, a);
                accum_point(cw.z, ca1.z, ca1.w, ca2.x, cb1.z, cb1.w, cb2.x, a);
                accum_point(cw.w, ca2.y, ca2.z, ca2.w, cb2.y, cb2.z, cb2.w, a);
                if (!more) break;
                ca0 = na0; ca1 = na1; ca2 = na2;
                cb0 = nb0; cb1 = nb1; cb2 = nb2; cw = nw;
            }
        }
    }
    // tail points (N % 4) — never taken for N = 4M, correctness-general
    if (blockIdx.x == 0 && t == 0) {
        for (int i = (N >> 2) << 2; i < N; ++i)
            accum_point(w[i], c0[3*i], c0[3*i+1], c0[3*i+2],
                        c1[3*i], c1[3*i+1], c1[3*i+2], a);
    }

    // ---- multi-value butterfly wave reduction: 32 accs in 32 shuffles.
    // final mapping lane -> acc = bitrev5(lane&31). ----
    {
        int hi;
        hi = lane & 1;
        #pragma unroll
        for (int i = 0; i < 16; ++i) {
            float send = hi ? a[i] : a[i + 16];
            float recv = __shfl_xor(send, 1, 64);
            a[i] = (hi ? a[i + 16] : a[i]) + recv;
        }
        hi = lane & 2;
        #pragma unroll
        for (int i = 0; i < 8; ++i) {
            float send = hi ? a[i] : a[i + 8];
            float recv = __shfl_xor(send, 2, 64);
            a[i] = (hi ? a[i + 8] : a[i]) + recv;
        }
        hi = lane & 4;
        #pragma unroll
        for (int i = 0; i < 4; ++i) {
            float send = hi ? a[i] : a[i + 4];
            float recv = __shfl_xor(send, 4, 64);
            a[i] = (hi ? a[i + 4] : a[i]) + recv;
        }
        hi = lane & 8;
        #pragma unroll
        for (int i = 0; i < 2; ++i) {
            float send = hi ? a[i] : a[i + 2];
            float recv = __shfl_xor(send, 8, 64);
            a[i] = (hi ? a[i + 2] : a[i]) + recv;
        }
        hi = lane & 16;
        {
            float send = hi ? a[0] : a[1];
            float recv = __shfl_xor(send, 16, 64);
            a[0] = (hi ? a[1] : a[0]) + recv;
        }
        a[0] += __shfl_xor(a[0], 32, 64);
    }
    if (lane < 32) {
        int acc = ((lane & 1) << 4) | ((lane & 2) << 2) | (lane & 4)
                | ((lane & 8) >> 2) | ((lane & 16) >> 4);  // bitrev5
        wred[wave][acc] = a[0];
    }
    __syncthreads();

    // ---- publish via native device-scope f32 atomic add (no fence);
    // one accumulator per 128B line -> parallel coherence handling ----
    if (t < NACC) {
        float val = wred[0][t] + wred[1][t] + wred[2][t] + wred[3][t];
        float* p = acc32 + (t << 5);   // t * ACC_STRIDE
        asm volatile("global_atomic_add_f32 %0, %1, off"
                     :: "v"(p), "v"(val) : "memory");
    }
    asm volatile("s_waitcnt vmcnt(0)" ::: "memory");  // fadds performed
    __syncthreads();
    __shared__ unsigned amlast;
    if (t == 0) amlast = atomicAdd(ticket, 1u);       // relaxed, coherent
    __syncthreads();
    if (amlast != (unsigned)(nblocks - 1)) return;

    // ---- last-arriving block: read totals via atomic fadd(0), sc0=return old
    __shared__ float tot[NACC];
    if (t < NACC) {
        float* p = acc32 + (t << 5);
        float zero = 0.0f, old;
        asm volatile("global_atomic_add_f32 %0, %1, %2, off sc0"
                     : "=&v"(old) : "v"(p), "v"(zero) : "memory");
        asm volatile("s_waitcnt vmcnt(0)" ::: "memory");
        tot[t] = old;
    }
    __syncthreads();
    if (t != 0) return;

    double d[NACC];
    #pragma unroll
    for (int i = 0; i < NACC; ++i) d[i] = (double)tot[i];

    const double EPSF = (double)1.1920929e-7f;  // float32 eps
    double cnt = d[0];
    double W = d[1];
    double swx[3] = { d[2], d[3], d[4] };
    double swy[3] = { d[5], d[6], d[7] };
    double swyx[9];
    for (int i = 0; i < 9; ++i) swyx[i] = d[8 + i];
    bool nep = cnt < 3.0;
    if (nep) {  // weights += EPS everywhere, applied analytically
        W += EPSF * (double)N;
        for (int i = 0; i < 3; ++i) { swx[i] += EPSF * d[17 + i]; swy[i] += EPSF * d[20 + i]; }
        for (int i = 0; i < 9; ++i) swyx[i] += EPSF * d[23 + i];
    }

    double mx[3], my[3];
    for (int i = 0; i < 3; ++i) { mx[i] = swx[i] / W; my[i] = swy[i] / W; }
    double S[3][3];
    for (int o = 0; o < 3; ++o)
        for (int i = 0; i < 3; ++i)
            S[o][i] = swyx[o * 3 + i] / W - my[o] * mx[i];

    // Jacobi eigendecomposition of B = S^T S  ->  V, lam
    double Bm[3][3], V[3][3];
    for (int i = 0; i < 3; ++i)
        for (int j = 0; j < 3; ++j) {
            double acc = 0.0;
            for (int k = 0; k < 3; ++k) acc += S[k][i] * S[k][j];
            Bm[i][j] = acc;
            V[i][j] = (i == j) ? 1.0 : 0.0;
        }
    for (int sweep = 0; sweep < 30; ++sweep) {
        double off2 = Bm[0][1]*Bm[0][1] + Bm[0][2]*Bm[0][2] + Bm[1][2]*Bm[1][2];
        double diag2 = Bm[0][0]*Bm[0][0] + Bm[1][1]*Bm[1][1] + Bm[2][2]*Bm[2][2];
        if (off2 <= diag2 * 1e-32 + 1e-300) break;
        for (int pair = 0; pair < 3; ++pair) {
            int p = (pair == 2) ? 1 : 0;
            int q = (pair == 0) ? 1 : 2;
            double apq = Bm[p][q];
            if (fabs(apq) < 1e-300) continue;
            double theta = (Bm[q][q] - Bm[p][p]) / (2.0 * apq);
            double tt = ((theta >= 0.0) ? 1.0 : -1.0) / (fabs(theta) + sqrt(1.0 + theta * theta));
            double c = 1.0 / sqrt(1.0 + tt * tt);
            double sn = tt * c;
            for (int k = 0; k < 3; ++k) {
                double bkp = Bm[k][p], bkq = Bm[k][q];
                Bm[k][p] = c * bkp - sn * bkq;
                Bm[k][q] = sn * bkp + c * bkq;
            }
            for (int k = 0; k < 3; ++k) {
                double bpk = Bm[p][k], bqk = Bm[q][k];
                Bm[p][k] = c * bpk - sn * bqk;
                Bm[q][k] = sn * bpk + c * bqk;
            }
            for (int k = 0; k < 3; ++k) {
                double vkp = V[k][p], vkq = V[k][q];
                V[k][p] = c * vkp - sn * vkq;
                V[k][q] = sn * vkp + c * vkq;
            }
        }
    }
    double lam[3] = { Bm[0][0], Bm[1][1], Bm[2][2] };
    for (int i = 0; i < 2; ++i)
        for (int j = i + 1; j < 3; ++j)
            if (lam[j] > lam[i]) {
                double tl = lam[i]; lam[i] = lam[j]; lam[j] = tl;
                for (int k = 0; k < 3; ++k) { double tv = V[k][i]; V[k][i] = V[k][j]; V[k][j] = tv; }
            }
    double sig[3];
    for (int i = 0; i < 3; ++i) sig[i] = sqrt(fmax(lam[i], 0.0));

    double U[3][3];
    for (int i = 0; i < 3; ++i) {
        double u0 = S[0][0]*V[0][i] + S[0][1]*V[1][i] + S[0][2]*V[2][i];
        double u1 = S[1][0]*V[0][i] + S[1][1]*V[1][i] + S[1][2]*V[2][i];
        double u2 = S[2][0]*V[0][i] + S[2][1]*V[1][i] + S[2][2]*V[2][i];
        double nrm = sqrt(u0*u0 + u1*u1 + u2*u2);
        if (nrm > 1e-150) {
            U[0][i] = u0 / nrm; U[1][i] = u1 / nrm; U[2][i] = u2 / nrm;
        } else if (i == 0) {
            U[0][0] = 1.0; U[1][0] = 0.0; U[2][0] = 0.0;
        } else if (i == 1) {
            double e0 = (fabs(U[0][0]) < 0.9) ? 1.0 : 0.0;
            double e1 = 1.0 - e0;
            double dp = e0 * U[0][0] + e1 * U[1][0];
            double v0 = e0 - dp * U[0][0], v1 = e1 - dp * U[1][0], v2 = -dp * U[2][0];
            double n2 = sqrt(v0*v0 + v1*v1 + v2*v2);
            U[0][1] = v0 / n2; U[1][1] = v1 / n2; U[2][1] = v2 / n2;
        } else {
            U[0][2] = U[1][0]*U[2][1] - U[2][0]*U[1][1];
            U[1][2] = U[2][0]*U[0][1] - U[0][0]*U[2][1];
            U[2][2] = U[0][0]*U[1][1] - U[1][0]*U[0][1];
        }
    }

    double tol = sig[0] * 3.0 * EPSF;
    int rank = (sig[0] > tol) + (sig[1] > tol) + (sig[2] > tol);
    double detS = det3(S);
    double det_mul = det3(U) * det3(V);
    double sign_full = (detS < 0.0) ? -1.0 : 1.0;
    double sign_def = (fabs(det_mul + 1.0) <= 1.00001e-5) ? -1.0 : 1.0;
    double s = (rank > 2) ? sign_full : sign_def;

    double R[3][3];
    for (int o = 0; o < 3; ++o)
        for (int i = 0; i < 3; ++i)
            R[o][i] = U[o][0]*V[i][0] + U[o][1]*V[i][1] + s * U[o][2]*V[i][2];
    double tv[3];
    for (int o = 0; o < 3; ++o)
        tv[o] = my[o] - (R[o][0]*mx[0] + R[o][1]*mx[1] + R[o][2]*mx[2]);

    for (int o = 0; o < 3; ++o) {
        out[o * 4 + 0] = (float)R[o][0];
        out[o * 4 + 1] = (float)R[o][1];
        out[o * 4 + 2] = (float)R[o][2];
        out[o * 4 + 3] = (float)tv[o];
    }
    out[12] = 0.0f; out[13] = 0.0f; out[14] = 0.0f; out[15] = 1.0f;
    out[16] = nep ? 1.0f : 0.0f;
}

extern "C" void kernel_launch(void* const* d_in, const int* in_sizes, int n_in,
                              void* d_out, int out_size, void* d_ws, size_t ws_size,
                              hipStream_t stream) {
    const float* c0 = (const float*)d_in[0];
    const float* c1 = (const float*)d_in[1];
    const float* w  = (const float*)d_in[2];
    float* out = (float*)d_out;
    int N = in_sizes[2];  // B=1: weights has N elements

    int ngrp = N >> 2;
    int blocks = (ngrp + 255) >> 8;
    if (blocks > 1024) blocks = 1024;   // N=4M -> 1024 blocks, 4 groups/thread
    if (blocks < 1) blocks = 1;

    float* acc32 = (float*)d_ws;   // 32 accs, each padded to its own 128B line
    unsigned* ticket = (unsigned*)((char*)d_ws + NACC * ACC_STRIDE * sizeof(float));

    hipMemsetAsync(d_ws, 0, NACC * ACC_STRIDE * sizeof(float) + sizeof(unsigned), stream);
    kabsch_fused<<<blocks, 256, 0, stream>>>(c0, c1, w, N, acc32, blocks, ticket, out);
}